// Round 11
// baseline (235.824 us; speedup 1.0000x reference)
//
#include <hip/hip_runtime.h>

#define NN 4096
#define DIM 128
#define TN 64            // q-rows per block
#define TM 64            // m-tile size
#define NSPLIT 8         // split-m factor
#define NTILES 8         // tiles per block (64 global tiles / 8)

typedef __attribute__((ext_vector_type(8))) short bf16x8;
typedef __attribute__((ext_vector_type(4))) float f32x4;

#define LSTRIDE 136                    // Hrow: ushorts per row (272 B)
#define HCST    72                     // Hcol: ushorts per row (144 B)
#define HROW_USH (TM * LSTRIDE)        // 8704 ushorts
#define HCOL_USH (DIM * HCST)          // 9216 ushorts
#define TILE_USH (HROW_USH + HCOL_USH) // 17920 ushorts = 35840 B
#define TILE_CHUNKS 35                 // 35840 / 1024
#define PWST 36                        // P row stride (72 B: 8B-aligned, conflict-free)
#define PW_USH (16 * PWST)             // 576 ushorts per wave

__device__ inline unsigned short f2bf(float x) {
    union { float f; unsigned u; } v; v.f = x;
    unsigned r = v.u + 0x7FFFu + ((v.u >> 16) & 1u);
    return (unsigned short)(r >> 16);
}

// async global->LDS DMA, 16 B/lane, dest = wave-uniform base + lane*16
__device__ inline void dma16(const void* g, void* l) {
    __builtin_amdgcn_global_load_lds(
        (const __attribute__((address_space(1))) void*)g,
        (__attribute__((address_space(3))) void*)l,
        16, 0, 0);
}

// ---- prep: hidden fp32 -> Hpack[64 tiles][Hrow 64x136 | Hcol 128x72] bf16 ----
__global__ __launch_bounds__(256) void prep_pack_kernel(
    const float* __restrict__ hidden,
    unsigned short* __restrict__ Hpack)
{
    __shared__ unsigned short T[DIM * HCST];
    const int tid = threadIdx.x;
    const int t0  = blockIdx.x;        // tile 0..63
    const int m0  = t0 * TM;
    unsigned short* rowdst = Hpack + (size_t)t0 * TILE_USH;
    unsigned short* coldst = rowdst + HROW_USH;

    #pragma unroll
    for (int it = 0; it < 8; ++it) {
        int idx = tid + 256 * it;      // 64 rows x 32 float4 chunks
        int row = idx >> 5;
        int c4  = (idx & 31) * 4;
        float4 v = *(const float4*)(hidden + (size_t)(m0 + row) * DIM + c4);
        ushort4 o;
        o.x = f2bf(v.x); o.y = f2bf(v.y); o.z = f2bf(v.z); o.w = f2bf(v.w);
        *(ushort4*)(rowdst + row * LSTRIDE + c4) = o;
        T[(c4 + 0) * HCST + row] = o.x;
        T[(c4 + 1) * HCST + row] = o.y;
        T[(c4 + 2) * HCST + row] = o.z;
        T[(c4 + 3) * HCST + row] = o.w;
    }
    __syncthreads();
    #pragma unroll
    for (int it = 0; it < 4; ++it) {
        int idx = tid + 256 * it;      // 128 d x 8 chunks of 8 ushorts
        int d  = idx >> 3;
        int c8 = (idx & 7) * 8;
        uint4 v = *(const uint4*)(T + d * HCST + c8);
        *(uint4*)(coldst + d * HCST + c8) = v;
    }
}

// ---- main: TN=64, wave-local P (no P barrier), 1 barrier/tile,
//      double-buffered DMA, direct adj loads ----
__global__ __launch_bounds__(512, 4) void gat_flash_kernel(
    const float* __restrict__ hidden,        // fp32 (Q only)
    const unsigned short* __restrict__ Hpack,
    const int*   __restrict__ adj,           // [NN][NN] int32
    const float* __restrict__ W,
    const float* __restrict__ bvec,
    float*       __restrict__ Opart,         // [512][TN][DIM]
    float*       __restrict__ lpart)         // [512][TN]
{
    __shared__ __align__(16) unsigned short HH[2][TILE_USH];   // 71680 B
    __shared__ __align__(16) unsigned short Plc[8 * PW_USH];   // 9216 B
    __shared__ float redsum[8][16];                            // 512 B

    const int tid  = threadIdx.x;
    const int w    = tid >> 6;
    const int lane = tid & 63;
    const int g    = lane >> 4;
    const int l15  = lane & 15;
    const int blk  = blockIdx.x;
    const int nbr  = blk >> 3;         // 0..63 row-group of 64
    const int q8   = blk & 7;
    const int n0   = nbr * TN;
    const int gt0  = q8 * NTILES;      // first global tile (of 64)
    const int rg   = w >> 1;           // 0..3: 16-row group
    const int ms   = w & 1;            // 0..1: 32-wide m-slice (QK and PV)
    const int lofs = lane * 16;
    const float NEG = -9.0e15f;

    const float b0 = bvec[0], b1 = bvec[1], b2 = bvec[2], b3 = bvec[3];

    // ---- prologue: DMA tile 0 -> HH[0] ----
    {
        const char* src = (const char*)(Hpack + (size_t)gt0 * TILE_USH);
        char* dst = (char*)&HH[0][0];
        #pragma unroll
        for (int it = 0; it < 5; ++it) {
            int chunk = it * 8 + w;
            if (chunk < TILE_CHUNKS)
                dma16(src + chunk * 1024 + lofs, dst + chunk * 1024);
        }
    }
    // ---- Af computed directly from global (no LDS round trip) ----
    bf16x8 Af[4][4];
    {
        const float* hr = hidden + (size_t)(n0 + rg * 16 + l15) * DIM;
        float4 hv[4][2];
        #pragma unroll
        for (int ks = 0; ks < 4; ++ks) {
            hv[ks][0] = *(const float4*)(hr + ks * 32 + 8 * g);
            hv[ks][1] = *(const float4*)(hr + ks * 32 + 8 * g + 4);
        }
        #pragma unroll
        for (int k = 0; k < 4; ++k) {
            const float* wr = W + k * DIM;
            #pragma unroll
            for (int ks = 0; ks < 4; ++ks) {
                float4 w0 = *(const float4*)(wr + ks * 32 + 8 * g);
                float4 w1 = *(const float4*)(wr + ks * 32 + 8 * g + 4);
                union { unsigned short u[8]; bf16x8 v; } c;
                c.u[0] = f2bf(hv[ks][0].x * w0.x);
                c.u[1] = f2bf(hv[ks][0].y * w0.y);
                c.u[2] = f2bf(hv[ks][0].z * w0.z);
                c.u[3] = f2bf(hv[ks][0].w * w0.w);
                c.u[4] = f2bf(hv[ks][1].x * w1.x);
                c.u[5] = f2bf(hv[ks][1].y * w1.y);
                c.u[6] = f2bf(hv[ks][1].z * w1.z);
                c.u[7] = f2bf(hv[ks][1].w * w1.w);
                Af[k][ks] = c.v;
            }
        }
    }

    float lrow[4] = {0.f, 0.f, 0.f, 0.f};
    f32x4 Oacc[8];
    #pragma unroll
    for (int dt = 0; dt < 8; ++dt) Oacc[dt] = (f32x4){0.f, 0.f, 0.f, 0.f};

    // adj codes for tile 0: 8 per lane (4 rows x 2 m-halves of the 32-slice)
    int avc[8], avn[8];
    #pragma unroll
    for (int i = 0; i < 8; ++i) avn[i] = 0;
    #pragma unroll
    for (int ch = 0; ch < 2; ++ch)
        #pragma unroll
        for (int t = 0; t < 4; ++t)
            avc[ch * 4 + t] = adj[(size_t)(n0 + rg * 16 + 4 * g + t) * NN
                                  + gt0 * TM + ms * 32 + ch * 16 + l15];

    __syncthreads();   // tile-0 DMA drained (vmcnt)

    unsigned short* Pw = &Plc[w * PW_USH];

    for (int tile = 0; tile < NTILES; ++tile) {
        const int cur = tile & 1;
        const int nxt = cur ^ 1;

        // ---- issue next-tile DMA + adj prefetch; in flight all tile ----
        if (tile + 1 < NTILES) {
            const char* src = (const char*)(Hpack + (size_t)(gt0 + tile + 1) * TILE_USH);
            char* dst = (char*)&HH[nxt][0];
            #pragma unroll
            for (int it = 0; it < 5; ++it) {
                int chunk = it * 8 + w;
                if (chunk < TILE_CHUNKS)
                    dma16(src + chunk * 1024 + lofs, dst + chunk * 1024);
            }
            #pragma unroll
            for (int ch = 0; ch < 2; ++ch)
                #pragma unroll
                for (int t = 0; t < 4; ++t)
                    avn[ch * 4 + t] = adj[(size_t)(n0 + rg * 16 + 4 * g + t) * NN
                                          + (gt0 + tile + 1) * TM + ms * 32 + ch * 16 + l15];
        }

        // ---- QK: S[k][ch] over own m-slice [ms*32, +32), rows rg*16..+16 ----
        f32x4 S[4][2];
        #pragma unroll
        for (int k = 0; k < 4; ++k) {
            S[k][0] = (f32x4){0.f, 0.f, 0.f, 0.f};
            S[k][1] = (f32x4){0.f, 0.f, 0.f, 0.f};
        }
        #pragma unroll
        for (int ks = 0; ks < 4; ++ks) {
            #pragma unroll
            for (int ch = 0; ch < 2; ++ch) {
                bf16x8 B = *(const bf16x8*)&HH[cur][(ms * 32 + ch * 16 + l15) * LSTRIDE + ks * 32 + 8 * g];
                #pragma unroll
                for (int k = 0; k < 4; ++k)
                    S[k][ch] = __builtin_amdgcn_mfma_f32_16x16x32_bf16(Af[k][ks], B, S[k][ch], 0, 0, 0);
            }
        }

        // ---- select + leakyrelu + exp; write wave-private P (no barrier) ----
        #pragma unroll
        for (int ch = 0; ch < 2; ++ch) {
            #pragma unroll
            for (int t = 0; t < 4; ++t) {
                int a = avc[ch * 4 + t];
                float s = S[0][ch][t] + b0;
                s = (a == 2) ? S[1][ch][t] + b1 : s;
                s = (a == 3) ? S[2][ch][t] + b2 : s;
                s = (a == 4) ? S[3][ch][t] + b3 : s;
                float e = fmaxf(s, 0.2f * s);
                e = (a == 0) ? NEG : e;
                float p = __expf(e);           // exp(-9e15) -> exactly 0
                lrow[t] += p;
                Pw[(4 * g + t) * PWST + ch * 16 + l15] = f2bf(p);
            }
        }

        // ---- wave-local P read-back as A-fragment (lgkm ordering only) ----
        union { uint2 u2[2]; bf16x8 v; } pc;
        {
            const uint2* pp = (const uint2*)&Pw[l15 * PWST + 8 * g];
            pc.u2[0] = pp[0];
            pc.u2[1] = pp[1];
        }
        bf16x8 Pa = pc.v;

        // ---- PV: own m-slice (K=32), all 128 d ----
        #pragma unroll
        for (int dt = 0; dt < 8; ++dt) {
            bf16x8 Bv = *(const bf16x8*)&HH[cur][HROW_USH + (dt * 16 + l15) * HCST + ms * 32 + 8 * g];
            Oacc[dt] = __builtin_amdgcn_mfma_f32_16x16x32_bf16(Pa, Bv, Oacc[dt], 0, 0, 0);
        }

        #pragma unroll
        for (int i = 0; i < 8; ++i) avc[i] = avn[i];
        __syncthreads();   // vmcnt(0) drain == "HH[nxt] staged"; buffer swap
    }

    // ---- epilogue: lrow lane-reduce; O cross-wave (ms pair) sum via HH ----
    #pragma unroll
    for (int t = 0; t < 4; ++t) {
        float v = lrow[t];
        v += __shfl_xor(v, 1); v += __shfl_xor(v, 2);
        v += __shfl_xor(v, 4); v += __shfl_xor(v, 8);
        if (l15 == 0) redsum[w][4 * g + t] = v;
    }
    float* HHf = (float*)&HH[0][0];    // 8 waves x 2048 floats = 64 KB
    #pragma unroll
    for (int dt = 0; dt < 8; ++dt)
        #pragma unroll
        for (int t = 0; t < 4; ++t)
            HHf[w * 2048 + (4 * g + t) * 128 + dt * 16 + l15] = Oacc[dt][t];
    __syncthreads();
    {
        float* Ob = Opart + (size_t)blk * (TN * DIM);
        #pragma unroll
        for (int i = 0; i < 16; ++i) {
            int e = tid + 512 * i;         // over 64*128
            int r = e >> 7, d = e & 127;
            int rg2 = r >> 4, rr = r & 15;
            float s = HHf[(rg2 * 2 + 0) * 2048 + rr * 128 + d]
                    + HHf[(rg2 * 2 + 1) * 2048 + rr * 128 + d];
            Ob[e] = s;
        }
        if (tid < TN) {
            int rg2 = tid >> 4, rr = tid & 15;
            lpart[blk * TN + tid] = redsum[rg2 * 2 + 0][rr] + redsum[rg2 * 2 + 1][rr];
        }
    }
}

// ---- combine the eight m-splits ----
__global__ __launch_bounds__(256) void combine_kernel(
    const float* __restrict__ Opart, const float* __restrict__ lpart,
    float* __restrict__ out)
{
    int idx = blockIdx.x * 256 + threadIdx.x;
    int r = idx >> 7, d = idx & 127;
    int nbr = r >> 6, rr = r & 63;
    float O = 0.f, l = 0.f;
    #pragma unroll
    for (int q = 0; q < NSPLIT; ++q) {
        O += Opart[(size_t)(nbr * NSPLIT + q) * (TN * DIM) + rr * 128 + d];
        l += lpart[(nbr * NSPLIT + q) * TN + rr];
    }
    out[idx] = O / l;
}

extern "C" void kernel_launch(void* const* d_in, const int* in_sizes, int n_in,
                              void* d_out, int out_size, void* d_ws, size_t ws_size,
                              hipStream_t stream) {
    const float* hidden = (const float*)d_in[0];
    const int*   adj    = (const int*)d_in[1];
    const float* W      = (const float*)d_in[2];
    const float* b      = (const float*)d_in[3];
    float* out = (float*)d_out;

    char* ws = (char*)d_ws;
    unsigned short* Hpack = (unsigned short*)ws;                 // 64*35840 = 2.29 MB
    float* Opart = (float*)(ws + (4u << 20));                    // 512*64*128*4 = 16 MB
    float* lpart = (float*)(ws + (20u << 20));                   // 128 KB

    prep_pack_kernel<<<NN / TM, 256, 0, stream>>>(hidden, Hpack);
    gat_flash_kernel<<<512, 512, 0, stream>>>(hidden, Hpack, adj, W, b, Opart, lpart);
    combine_kernel<<<NN * DIM / 256, 256, 0, stream>>>(Opart, lpart, out);
}

// Round 12
// 138.739 us; speedup vs baseline: 1.6998x; 1.6998x over previous
//
#include <hip/hip_runtime.h>

#define NN 4096
#define DIM 128
#define TN 32            // q-rows per block
#define TM 128           // m-tile size
#define NTILES 16        // tiles per block (half of the 32 global tiles)

typedef __attribute__((ext_vector_type(8))) short bf16x8;
typedef __attribute__((ext_vector_type(4))) float f32x4;

#define LSTRIDE 136                    // ushorts per row (272 B, 16B-aligned)
#define REGION  (128 * LSTRIDE)        // one layout region (34816 ushorts)
#define TILE_USH (2 * REGION)          // Hrow|Hcol per tile = 69632 B
#define TILE_CHUNKS 68                 // 69632 / 1024
#define PST 136                        // P row stride (ushorts)

__device__ inline unsigned short f2bf(float x) {
    union { float f; unsigned u; } v; v.f = x;
    unsigned r = v.u + 0x7FFFu + ((v.u >> 16) & 1u);
    return (unsigned short)(r >> 16);
}

// async global->LDS DMA, 16 B/lane, dest = wave-uniform base + lane*16
__device__ inline void dma16(const void* g, void* l) {
    __builtin_amdgcn_global_load_lds(
        (const __attribute__((address_space(1))) void*)g,
        (__attribute__((address_space(3))) void*)l,
        16, 0, 0);
}

// ---- prep: hidden fp32 -> Hpack[32 tiles][Hrow region | Hcol region] ----
__global__ __launch_bounds__(256) void prep_pack_kernel(
    const float* __restrict__ hidden,
    unsigned short* __restrict__ Hpack)
{
    __shared__ unsigned short T[128 * LSTRIDE];
    const int tid = threadIdx.x;
    const int t0  = blockIdx.x;
    const int m0  = t0 * TM;
    unsigned short* rowdst = Hpack + (size_t)t0 * TILE_USH;
    unsigned short* coldst = rowdst + REGION;

    #pragma unroll
    for (int it = 0; it < 16; ++it) {
        int idx = tid + 256 * it;
        int row = idx >> 5;
        int c4  = (idx & 31) * 4;
        float4 v = *(const float4*)(hidden + (size_t)(m0 + row) * DIM + c4);
        ushort4 o;
        o.x = f2bf(v.x); o.y = f2bf(v.y); o.z = f2bf(v.z); o.w = f2bf(v.w);
        *(ushort4*)(rowdst + row * LSTRIDE + c4) = o;
        T[(c4 + 0) * LSTRIDE + row] = o.x;
        T[(c4 + 1) * LSTRIDE + row] = o.y;
        T[(c4 + 2) * LSTRIDE + row] = o.z;
        T[(c4 + 3) * LSTRIDE + row] = o.w;
    }
    __syncthreads();
    #pragma unroll
    for (int it = 0; it < 8; ++it) {
        int idx = tid + 256 * it;
        int d  = idx >> 4;
        int c8 = (idx & 15) * 8;
        uint4 v = *(const uint4*)(T + d * LSTRIDE + c8);
        *(uint4*)(coldst + d * LSTRIDE + c8) = v;
    }
}

// ---- main: TN=32, double-buffered DMA pipeline (global_load_lds),
//      lgkm-only mid barrier, DIRECT adj int32 loads (no prep_adj) ----
__global__ __launch_bounds__(512, 2) void gat_flash_kernel(
    const float* __restrict__ hidden,        // fp32 (Q only)
    const unsigned short* __restrict__ Hpack,
    const int*   __restrict__ adj,           // [NN][NN] int32, read direct
    const float* __restrict__ W,
    const float* __restrict__ bvec,
    float*       __restrict__ Opart,         // [256][TN][DIM]
    float*       __restrict__ lpart)         // [256][TN]
{
    __shared__ __align__(16) unsigned short HH[2][TILE_USH];   // 139264 B
    __shared__ __align__(16) unsigned short Plc[TN * PST];     // 8704 B
    __shared__ float redsum[8][16];

    const int tid  = threadIdx.x;
    const int w    = tid >> 6;
    const int lane = tid & 63;
    const int g    = lane >> 4;
    const int l15  = lane & 15;
    const int blk  = blockIdx.x;
    const int nb   = blk >> 1;         // 0..127 row-group of 32
    const int half = blk & 1;
    const int n0   = nb * TN;
    const int gt0  = half * NTILES;
    const int rg   = w >> 2;           // 0/1: which 16-row group
    const int ms   = w & 3;            // QK m-slice (32 wide) / PV d-quarter
    const int lofs = lane * 16;
    const float NEG = -9.0e15f;

    const float b0 = bvec[0], b1 = bvec[1], b2 = bvec[2], b3 = bvec[3];

    // ---- prologue: DMA tile 0 -> HH[0] (overlaps Q compute below) ----
    {
        const char* src = (const char*)(Hpack + (size_t)gt0 * TILE_USH);
        char* dst = (char*)&HH[0][0];
        #pragma unroll
        for (int it = 0; it < 9; ++it) {
            int chunk = it * 8 + w;
            if (chunk < TILE_CHUNKS)
                dma16(src + chunk * 1024 + lofs, dst + chunk * 1024);
        }
    }
    // Q into HH[1] rows k*32+r
    {
        int qr = tid >> 2;             // 0..127 = k*32 + r
        int r  = qr & 31;
        int d0 = (tid & 3) * 32;
        const float* hrow = hidden + (size_t)(n0 + r) * DIM + d0;
        const float* wrow = W + (qr >> 5) * DIM + d0;
        unsigned short* qdst = &HH[1][qr * LSTRIDE + d0];
        #pragma unroll
        for (int c = 0; c < 8; ++c) {
            float4 hv = *(const float4*)(hrow + 4 * c);
            float4 wv = *(const float4*)(wrow + 4 * c);
            ushort4 o;
            o.x = f2bf(hv.x * wv.x); o.y = f2bf(hv.y * wv.y);
            o.z = f2bf(hv.z * wv.z); o.w = f2bf(hv.w * wv.w);
            *(ushort4*)(qdst + 4 * c) = o;
        }
    }
    __syncthreads();   // drains tile-0 DMA (vmcnt) + Q LDS writes (lgkm)

    // A-fragments for this wave's 16 rows; HH[1] becomes a staging buffer
    // after the next barrier
    bf16x8 Af[4][4];
    #pragma unroll
    for (int k = 0; k < 4; ++k)
        #pragma unroll
        for (int ks = 0; ks < 4; ++ks)
            Af[k][ks] = *(const bf16x8*)&HH[1][(k * 32 + rg * 16 + l15) * LSTRIDE + ks * 32 + 8 * g];
    __syncthreads();   // Af reads drained before tile-1 DMA may write HH[1]

    float lrow[4] = {0.f, 0.f, 0.f, 0.f};
    f32x4 Oacc[2];
    Oacc[0] = (f32x4){0.f, 0.f, 0.f, 0.f};
    Oacc[1] = (f32x4){0.f, 0.f, 0.f, 0.f};

    // direct adj codes for tile 0: 8 coalesced int loads/lane
    const size_t arow = (size_t)(n0 + rg * 16 + 4 * g) * NN;   // row of t=0
    int avc[8], avn[8];
    #pragma unroll
    for (int ch = 0; ch < 2; ++ch)
        #pragma unroll
        for (int t = 0; t < 4; ++t)
            avc[ch * 4 + t] = adj[arow + (size_t)t * NN + gt0 * TM + ms * 32 + ch * 16 + l15];

    for (int tile = 0; tile < NTILES; ++tile) {
        const int cur = tile & 1;
        const int nxt = cur ^ 1;

        // ---- issue next-tile DMA + adj prefetch; stays in flight all tile ----
        if (tile + 1 < NTILES) {
            const char* src = (const char*)(Hpack + (size_t)(gt0 + tile + 1) * TILE_USH);
            char* dst = (char*)&HH[nxt][0];
            #pragma unroll
            for (int it = 0; it < 9; ++it) {
                int chunk = it * 8 + w;
                if (chunk < TILE_CHUNKS)
                    dma16(src + chunk * 1024 + lofs, dst + chunk * 1024);
            }
            #pragma unroll
            for (int ch = 0; ch < 2; ++ch)
                #pragma unroll
                for (int t = 0; t < 4; ++t)
                    avn[ch * 4 + t] = adj[arow + (size_t)t * NN + (gt0 + tile + 1) * TM + ms * 32 + ch * 16 + l15];
        }

        // ---- QK: S[k][ch] over m-slice [ms*32, +32) for rows rg*16..+16 ----
        f32x4 S[4][2];
        #pragma unroll
        for (int k = 0; k < 4; ++k) {
            S[k][0] = (f32x4){0.f, 0.f, 0.f, 0.f};
            S[k][1] = (f32x4){0.f, 0.f, 0.f, 0.f};
        }
        #pragma unroll
        for (int ks = 0; ks < 4; ++ks) {
            #pragma unroll
            for (int ch = 0; ch < 2; ++ch) {
                bf16x8 B = *(const bf16x8*)&HH[cur][(ms * 32 + ch * 16 + l15) * LSTRIDE + ks * 32 + 8 * g];
                #pragma unroll
                for (int k = 0; k < 4; ++k)
                    S[k][ch] = __builtin_amdgcn_mfma_f32_16x16x32_bf16(Af[k][ks], B, S[k][ch], 0, 0, 0);
            }
        }

        // ---- select + leakyrelu + exp (no-max softmax; scores bounded) ----
        #pragma unroll
        for (int ch = 0; ch < 2; ++ch) {
            #pragma unroll
            for (int t = 0; t < 4; ++t) {
                int a = avc[ch * 4 + t];
                float s = S[0][ch][t] + b0;
                s = (a == 2) ? S[1][ch][t] + b1 : s;
                s = (a == 3) ? S[2][ch][t] + b2 : s;
                s = (a == 4) ? S[3][ch][t] + b3 : s;
                float e = fmaxf(s, 0.2f * s);
                e = (a == 0) ? NEG : e;
                float p = __expf(e);           // exp(-9e15) -> exactly 0
                lrow[t] += p;
                Plc[(rg * 16 + 4 * g + t) * PST + ms * 32 + ch * 16 + l15] = f2bf(p);
            }
        }

        // ---- P-ready barrier: LDS-only drain; DMA stays in flight ----
        asm volatile("s_waitcnt lgkmcnt(0)\n\ts_barrier" ::: "memory");

        // ---- PV: rows rg*16..+16, d-quarter [ms*32, +32), K=128 ----
        #pragma unroll
        for (int c4 = 0; c4 < 4; ++c4) {
            bf16x8 Pa = *(const bf16x8*)&Plc[(rg * 16 + l15) * PST + c4 * 32 + 8 * g];
            #pragma unroll
            for (int dt = 0; dt < 2; ++dt) {
                bf16x8 Bv = *(const bf16x8*)&HH[cur][REGION + (ms * 32 + dt * 16 + l15) * LSTRIDE + c4 * 32 + 8 * g];
                Oacc[dt] = __builtin_amdgcn_mfma_f32_16x16x32_bf16(Pa, Bv, Oacc[dt], 0, 0, 0);
            }
        }

        #pragma unroll
        for (int i = 0; i < 8; ++i) avc[i] = avn[i];
        __syncthreads();   // vmcnt(0) drain == "HH[nxt] staged"; buffer swap
    }

    // ---- epilogue ----
    #pragma unroll
    for (int t = 0; t < 4; ++t) {
        float v = lrow[t];
        v += __shfl_xor(v, 1); v += __shfl_xor(v, 2);
        v += __shfl_xor(v, 4); v += __shfl_xor(v, 8);
        if (l15 == 0) redsum[w][4 * g + t] = v;
    }
    __syncthreads();
    if (tid < 32) {
        int rgp = tid >> 4, rr = tid & 15;
        float s = redsum[rgp * 4 + 0][rr] + redsum[rgp * 4 + 1][rr]
                + redsum[rgp * 4 + 2][rr] + redsum[rgp * 4 + 3][rr];
        lpart[blk * 32 + tid] = s;
    }
    float* Ob = Opart + (size_t)blk * TN * DIM;
    #pragma unroll
    for (int dt = 0; dt < 2; ++dt)
        #pragma unroll
        for (int t = 0; t < 4; ++t)
            Ob[(rg * 16 + 4 * g + t) * DIM + ms * 32 + dt * 16 + l15] = Oacc[dt][t];
}

// ---- combine the two m-halves ----
__global__ __launch_bounds__(256) void combine_kernel(
    const float* __restrict__ Opart, const float* __restrict__ lpart,
    float* __restrict__ out)
{
    int idx = blockIdx.x * 256 + threadIdx.x;
    int r = idx >> 7, d = idx & 127;
    int nb = r >> 5, rr = r & 31;
    float O0 = Opart[(size_t)(nb * 2) * (TN * DIM) + rr * 128 + d];
    float O1 = Opart[(size_t)(nb * 2 + 1) * (TN * DIM) + rr * 128 + d];
    float l0 = lpart[(nb * 2) * 32 + rr];
    float l1 = lpart[(nb * 2 + 1) * 32 + rr];
    out[idx] = (O0 + O1) / (l0 + l1);
}

extern "C" void kernel_launch(void* const* d_in, const int* in_sizes, int n_in,
                              void* d_out, int out_size, void* d_ws, size_t ws_size,
                              hipStream_t stream) {
    const float* hidden = (const float*)d_in[0];
    const int*   adj    = (const int*)d_in[1];
    const float* W      = (const float*)d_in[2];
    const float* b      = (const float*)d_in[3];
    float* out = (float*)d_out;

    char* ws = (char*)d_ws;
    unsigned short* Hpack = (unsigned short*)ws;                 // 2.18 MB
    float* Opart = (float*)(ws + (4u << 20));                    // 4 MB
    float* lpart = (float*)(ws + (8u << 20));                    // 32 KB

    prep_pack_kernel<<<NN / TM, 256, 0, stream>>>(hidden, Hpack);
    gat_flash_kernel<<<256, 512, 0, stream>>>(hidden, Hpack, adj, W, b, Opart, lpart);
    combine_kernel<<<NN * DIM / 256, 256, 0, stream>>>(Opart, lpart, out);
}

// Round 13
// 135.479 us; speedup vs baseline: 1.7407x; 1.0241x over previous
//
#include <hip/hip_runtime.h>

#define NN 4096
#define DIM 128
#define TN 64            // q-rows per block
#define TM 128           // m-tile size
#define NSPLIT 4         // split-m factor
#define NTILES 8         // tiles per block (32 global tiles / 4)

typedef __attribute__((ext_vector_type(8))) short bf16x8;
typedef __attribute__((ext_vector_type(4))) float f32x4;

#define LSTRIDE 136                    // ushorts per row (272 B, 16B-aligned)
#define REGION  (128 * LSTRIDE)        // one layout region (34816 ushorts)
#define TILE_USH (2 * REGION)          // Hrow|Hcol per tile = 69632 B
#define TILE_CHUNKS 68                 // 69632 / 1024
#define PST 136                        // P row stride (ushorts)

__device__ inline unsigned short f2bf(float x) {
    union { float f; unsigned u; } v; v.f = x;
    unsigned r = v.u + 0x7FFFu + ((v.u >> 16) & 1u);
    return (unsigned short)(r >> 16);
}

// async global->LDS DMA, 16 B/lane, dest = wave-uniform base + lane*16
__device__ inline void dma16(const void* g, void* l) {
    __builtin_amdgcn_global_load_lds(
        (const __attribute__((address_space(1))) void*)g,
        (__attribute__((address_space(3))) void*)l,
        16, 0, 0);
}

// ---- prep: hidden fp32 -> Hpack[32 tiles][Hrow region | Hcol region] ----
__global__ __launch_bounds__(256) void prep_pack_kernel(
    const float* __restrict__ hidden,
    unsigned short* __restrict__ Hpack)
{
    __shared__ unsigned short T[128 * LSTRIDE];
    const int tid = threadIdx.x;
    const int t0  = blockIdx.x;
    const int m0  = t0 * TM;
    unsigned short* rowdst = Hpack + (size_t)t0 * TILE_USH;
    unsigned short* coldst = rowdst + REGION;

    #pragma unroll
    for (int it = 0; it < 16; ++it) {
        int idx = tid + 256 * it;
        int row = idx >> 5;
        int c4  = (idx & 31) * 4;
        float4 v = *(const float4*)(hidden + (size_t)(m0 + row) * DIM + c4);
        ushort4 o;
        o.x = f2bf(v.x); o.y = f2bf(v.y); o.z = f2bf(v.z); o.w = f2bf(v.w);
        *(ushort4*)(rowdst + row * LSTRIDE + c4) = o;
        T[(c4 + 0) * LSTRIDE + row] = o.x;
        T[(c4 + 1) * LSTRIDE + row] = o.y;
        T[(c4 + 2) * LSTRIDE + row] = o.z;
        T[(c4 + 3) * LSTRIDE + row] = o.w;
    }
    __syncthreads();
    #pragma unroll
    for (int it = 0; it < 8; ++it) {
        int idx = tid + 256 * it;
        int d  = idx >> 4;
        int c8 = (idx & 15) * 8;
        uint4 v = *(const uint4*)(T + d * LSTRIDE + c8);
        *(uint4*)(coldst + d * LSTRIDE + c8) = v;
    }
}

// ---- main: TN=64, 8 waves = 4 row-groups x 2 slices, double-buffered DMA,
//      lgkm-only mid barrier, direct adj loads, disjoint O ownership ----
__global__ __launch_bounds__(512, 2) void gat_flash_kernel(
    const float* __restrict__ hidden,        // fp32 (Q only)
    const unsigned short* __restrict__ Hpack,
    const int*   __restrict__ adj,           // [NN][NN] int32
    const float* __restrict__ W,
    const float* __restrict__ bvec,
    float*       __restrict__ Opart,         // [256][TN][DIM]
    float*       __restrict__ lpart)         // [256][TN]
{
    __shared__ __align__(16) unsigned short HH[2][TILE_USH];   // 139264 B
    __shared__ __align__(16) unsigned short Plc[TN * PST];     // 17408 B
    __shared__ float redsum[8][16];                            // 512 B

    const int tid  = threadIdx.x;
    const int w    = tid >> 6;
    const int lane = tid & 63;
    const int g    = lane >> 4;
    const int l15  = lane & 15;
    const int blk  = blockIdx.x;
    const int nbr  = blk >> 2;         // 0..63 row-group of 64
    const int q4   = blk & 3;
    const int n0   = nbr * TN;
    const int gt0  = q4 * NTILES;      // first global tile (of 32)
    const int rg   = w >> 1;           // 0..3: 16-row group
    const int msw  = w & 1;            // 0..1: 64-wide m-slice (QK) / d-half (PV)
    const int lofs = lane * 16;
    const float NEG = -9.0e15f;

    const float b0 = bvec[0], b1 = bvec[1], b2 = bvec[2], b3 = bvec[3];

    // ---- prologue: DMA tile 0 -> HH[0] (overlaps Q compute below) ----
    {
        const char* src = (const char*)(Hpack + (size_t)gt0 * TILE_USH);
        char* dst = (char*)&HH[0][0];
        #pragma unroll
        for (int it = 0; it < 9; ++it) {
            int chunk = it * 8 + w;
            if (chunk < TILE_CHUNKS)
                dma16(src + chunk * 1024 + lofs, dst + chunk * 1024);
        }
    }
    // Q into HH[1]: 256 rows (k*64 + r) x 128 d == exactly TILE_USH
    {
        #pragma unroll
        for (int it = 0; it < 4; ++it) {
            int idx = tid + 512 * it;      // 0..2047
            int row = idx >> 3;            // 0..255 = k*64 + r
            int c16 = (idx & 7) * 16;
            int k = row >> 6, r = row & 63;
            const float* hrow = hidden + (size_t)(n0 + r) * DIM + c16;
            const float* wrow = W + k * DIM + c16;
            unsigned short* qdst = &HH[1][row * LSTRIDE + c16];
            #pragma unroll
            for (int c = 0; c < 4; ++c) {
                float4 hv = *(const float4*)(hrow + 4 * c);
                float4 wv = *(const float4*)(wrow + 4 * c);
                ushort4 o;
                o.x = f2bf(hv.x * wv.x); o.y = f2bf(hv.y * wv.y);
                o.z = f2bf(hv.z * wv.z); o.w = f2bf(hv.w * wv.w);
                *(ushort4*)(qdst + 4 * c) = o;
            }
        }
    }
    __syncthreads();   // drains tile-0 DMA (vmcnt) + Q LDS writes (lgkm)

    // A-fragments for this wave's 16 rows; HH[1] becomes a staging buffer
    bf16x8 Af[4][4];
    #pragma unroll
    for (int k = 0; k < 4; ++k)
        #pragma unroll
        for (int ks = 0; ks < 4; ++ks)
            Af[k][ks] = *(const bf16x8*)&HH[1][(k * 64 + rg * 16 + l15) * LSTRIDE + ks * 32 + 8 * g];
    __syncthreads();   // Af reads drained before tile-1 DMA may write HH[1]

    float lrow[4] = {0.f, 0.f, 0.f, 0.f};
    f32x4 Oacc[4];
    #pragma unroll
    for (int dt = 0; dt < 4; ++dt) Oacc[dt] = (f32x4){0.f, 0.f, 0.f, 0.f};

    // direct adj codes for tile 0: 16 coalesced int loads/lane
    const size_t arow = (size_t)(n0 + rg * 16 + 4 * g) * NN;   // row of t=0
    int avc[16], avn[16];
    #pragma unroll
    for (int ch = 0; ch < 4; ++ch)
        #pragma unroll
        for (int t = 0; t < 4; ++t)
            avc[ch * 4 + t] = adj[arow + (size_t)t * NN + gt0 * TM + msw * 64 + ch * 16 + l15];

    for (int tile = 0; tile < NTILES; ++tile) {
        const int cur = tile & 1;
        const int nxt = cur ^ 1;

        // ---- issue next-tile DMA + adj prefetch; stays in flight all tile ----
        if (tile + 1 < NTILES) {
            const char* src = (const char*)(Hpack + (size_t)(gt0 + tile + 1) * TILE_USH);
            char* dst = (char*)&HH[nxt][0];
            #pragma unroll
            for (int it = 0; it < 9; ++it) {
                int chunk = it * 8 + w;
                if (chunk < TILE_CHUNKS)
                    dma16(src + chunk * 1024 + lofs, dst + chunk * 1024);
            }
            #pragma unroll
            for (int ch = 0; ch < 4; ++ch)
                #pragma unroll
                for (int t = 0; t < 4; ++t)
                    avn[ch * 4 + t] = adj[arow + (size_t)t * NN + (gt0 + tile + 1) * TM + msw * 64 + ch * 16 + l15];
        }

        // ---- QK: S[k][ch] over m-slice [msw*64, +64) for rows rg*16..+16 ----
        f32x4 S[4][4];
        #pragma unroll
        for (int k = 0; k < 4; ++k)
            #pragma unroll
            for (int ch = 0; ch < 4; ++ch)
                S[k][ch] = (f32x4){0.f, 0.f, 0.f, 0.f};
        #pragma unroll
        for (int ks = 0; ks < 4; ++ks) {
            #pragma unroll
            for (int ch = 0; ch < 4; ++ch) {
                bf16x8 B = *(const bf16x8*)&HH[cur][(msw * 64 + ch * 16 + l15) * LSTRIDE + ks * 32 + 8 * g];
                #pragma unroll
                for (int k = 0; k < 4; ++k)
                    S[k][ch] = __builtin_amdgcn_mfma_f32_16x16x32_bf16(Af[k][ks], B, S[k][ch], 0, 0, 0);
            }
        }

        // ---- select + leakyrelu + exp (no-max softmax; scores bounded) ----
        #pragma unroll
        for (int ch = 0; ch < 4; ++ch) {
            #pragma unroll
            for (int t = 0; t < 4; ++t) {
                int a = avc[ch * 4 + t];
                float s = S[0][ch][t] + b0;
                s = (a == 2) ? S[1][ch][t] + b1 : s;
                s = (a == 3) ? S[2][ch][t] + b2 : s;
                s = (a == 4) ? S[3][ch][t] + b3 : s;
                float e = fmaxf(s, 0.2f * s);
                e = (a == 0) ? NEG : e;
                float p = __expf(e);           // exp(-9e15) -> exactly 0
                lrow[t] += p;
                Plc[(rg * 16 + 4 * g + t) * PST + msw * 64 + ch * 16 + l15] = f2bf(p);
            }
        }

        // ---- P-ready barrier: LDS-only drain; DMA stays in flight ----
        asm volatile("s_waitcnt lgkmcnt(0)\n\ts_barrier" ::: "memory");

        // ---- PV: rows rg*16..+16, d-half [msw*64, +64), K=128 ----
        #pragma unroll
        for (int c4 = 0; c4 < 4; ++c4) {
            bf16x8 Pa = *(const bf16x8*)&Plc[(rg * 16 + l15) * PST + c4 * 32 + 8 * g];
            #pragma unroll
            for (int dt = 0; dt < 4; ++dt) {
                bf16x8 Bv = *(const bf16x8*)&HH[cur][REGION + (msw * 64 + dt * 16 + l15) * LSTRIDE + c4 * 32 + 8 * g];
                Oacc[dt] = __builtin_amdgcn_mfma_f32_16x16x32_bf16(Pa, Bv, Oacc[dt], 0, 0, 0);
            }
        }

        #pragma unroll
        for (int i = 0; i < 16; ++i) avc[i] = avn[i];
        __syncthreads();   // vmcnt(0) drain == "HH[nxt] staged"; buffer swap
    }

    // ---- epilogue: O is wave-disjoint (rg, msw) -> direct store ----
    #pragma unroll
    for (int t = 0; t < 4; ++t) {
        float v = lrow[t];
        v += __shfl_xor(v, 1); v += __shfl_xor(v, 2);
        v += __shfl_xor(v, 4); v += __shfl_xor(v, 8);
        if (l15 == 0) redsum[w][4 * g + t] = v;
    }
    __syncthreads();
    if (tid < TN) {
        int rg2 = tid >> 4, rr = tid & 15;
        lpart[blk * TN + tid] = redsum[rg2 * 2 + 0][rr] + redsum[rg2 * 2 + 1][rr];
    }
    float* Ob = Opart + (size_t)blk * (TN * DIM);
    #pragma unroll
    for (int dt = 0; dt < 4; ++dt)
        #pragma unroll
        for (int t = 0; t < 4; ++t)
            Ob[(rg * 16 + 4 * g + t) * DIM + msw * 64 + dt * 16 + l15] = Oacc[dt][t];
}

// ---- combine the four m-quarters ----
__global__ __launch_bounds__(256) void combine_kernel(
    const float* __restrict__ Opart, const float* __restrict__ lpart,
    float* __restrict__ out)
{
    int idx = blockIdx.x * 256 + threadIdx.x;
    int r = idx >> 7, d = idx & 127;
    int nbr = r >> 6, rr = r & 63;
    float O = 0.f, l = 0.f;
    #pragma unroll
    for (int q = 0; q < NSPLIT; ++q) {
        O += Opart[(size_t)(nbr * NSPLIT + q) * (TN * DIM) + rr * 128 + d];
        l += lpart[(nbr * NSPLIT + q) * TN + rr];
    }
    out[idx] = O / l;
}

extern "C" void kernel_launch(void* const* d_in, const int* in_sizes, int n_in,
                              void* d_out, int out_size, void* d_ws, size_t ws_size,
                              hipStream_t stream) {
    const float* hidden = (const float*)d_in[0];
    const int*   adj    = (const int*)d_in[1];
    const float* W      = (const float*)d_in[2];
    const float* b      = (const float*)d_in[3];
    float* out = (float*)d_out;

    char* ws = (char*)d_ws;
    unsigned short* Hpack = (unsigned short*)ws;                 // 2.18 MB
    float* Opart = (float*)(ws + (4u << 20));                    // 256*64*128*4 = 8 MB
    float* lpart = (float*)(ws + (12u << 20));                   // 64 KB

    prep_pack_kernel<<<NN / TM, 256, 0, stream>>>(hidden, Hpack);
    gat_flash_kernel<<<256, 512, 0, stream>>>(hidden, Hpack, adj, W, b, Opart, lpart);
    combine_kernel<<<NN * DIM / 256, 256, 0, stream>>>(Opart, lpart, out);
}